// Round 2
// baseline (133.843 us; speedup 1.0000x reference)
//
#include <hip/hip_runtime.h>
#include <hip/hip_bf16.h>

#define LSEQ 8192
#define E 1024
#define H 16

typedef __attribute__((ext_vector_type(8))) short short8;
typedef __attribute__((ext_vector_type(4))) float f32x4;

__device__ inline unsigned short f2bf(float f) {
    union { float f; unsigned int i; } v; v.f = f;
    unsigned int x = v.i;
    unsigned int r = (x + 0x7fffu + ((x >> 16) & 1u)) >> 16;
    return (unsigned short)r;
}

__device__ inline float wave_reduce_sum(float v) {
    #pragma unroll
    for (int off = 32; off > 0; off >>= 1) v += __shfl_xor(v, off, 64);
    return v;
}

// K0: q[i] = Wq[i,:] . x0 + bq[i], i in [0,1024). One wave per output.
__global__ __launch_bounds__(256) void k0_q(
    const float* __restrict__ x, const float* __restrict__ W,
    const float* __restrict__ bias, float* __restrict__ q_ws)
{
    int wave = threadIdx.x >> 6, lane = threadIdx.x & 63;
    int i = blockIdx.x * 4 + wave;
    const f32x4* wp = (const f32x4*)(W + i * E) + lane * 4;
    const f32x4* xp = (const f32x4*)(x) + lane * 4;
    float s = 0.f;
    #pragma unroll
    for (int j = 0; j < 4; j++) {
        f32x4 w4 = wp[j], x4 = xp[j];
        s += w4[0] * x4[0] + w4[1] * x4[1] + w4[2] * x4[2] + w4[3] * x4[3];
    }
    s = wave_reduce_sum(s);
    if (lane == 0) q_ws[i] = s + bias[i];
}

// K1: r_bf[h][e] = bf16(0.125 * sum_d q[h*64+d] * Wk[h*64+d, e]);
//     c[h] = 0.125 * q_h . bk_h
// grid 256: hb = b>>4, col chunk = (b&15)*64
__global__ __launch_bounds__(256) void k1_rc(
    const float* __restrict__ W, const float* __restrict__ bias,
    const float* __restrict__ q_ws, unsigned short* __restrict__ r_bf,
    float* __restrict__ c_ws)
{
    __shared__ float red[4][64];
    int hb = blockIdx.x >> 4, ec = blockIdx.x & 15;
    int lane = threadIdx.x & 63, wq = threadIdx.x >> 6;
    int e = ec * 64 + lane;
    const float* qh = q_ws + hb * 64;
    float acc = 0.f;
    #pragma unroll
    for (int i = 0; i < 16; i++) {
        int d = wq * 16 + i;
        acc += qh[d] * W[(E + hb * 64 + d) * E + e];
    }
    red[wq][lane] = acc;
    __syncthreads();
    if (wq == 0) {
        float s = red[0][lane] + red[1][lane] + red[2][lane] + red[3][lane];
        r_bf[hb * E + e] = f2bf(s * 0.125f);
    }
    if (ec == 0 && wq == 1) {
        float v = qh[lane] * bias[E + hb * 64 + lane];
        v = wave_reduce_sum(v);
        if (lane == 0) c_ws[hb] = v * 0.125f;
    }
}

// K2: scores[h][l] = x[l,:] . r_h + c_h  via MFMA 16x16x32 bf16 (x cvt'd on the fly).
// 256 blocks x 4 waves; waves pair up: 2 m-tiles per block, K split in halves of 512.
__global__ __launch_bounds__(256) void k2_scores(
    const float* __restrict__ x,
    const unsigned short* __restrict__ r_bf,
    const float* __restrict__ c_ws,
    float* __restrict__ scores)
{
    __shared__ f32x4 comb[2][64];
    int tid = threadIdx.x;
    int wave = tid >> 6, lane = tid & 63;
    int mloc = wave >> 1, khalf = wave & 1;
    int mtile = blockIdx.x * 2 + mloc;    // 0..511
    int mbase = mtile * 16;
    int rw = lane & 15, quad = lane >> 4;
    float cv = (khalf == 0) ? c_ws[rw] : 0.f;
    f32x4 acc = {cv, cv, cv, cv};
    const f32x4* ap = (const f32x4*)(x + (mbase + rw) * E + khalf * 512) + quad * 2;
    const short8* bp = (const short8*)(r_bf + rw * E + khalf * 512) + quad;
    #pragma unroll 4
    for (int kk = 0; kk < 16; kk++) {
        f32x4 a0 = ap[kk * 8];
        f32x4 a1 = ap[kk * 8 + 1];
        short8 af;
        af[0] = (short)f2bf(a0[0]); af[1] = (short)f2bf(a0[1]);
        af[2] = (short)f2bf(a0[2]); af[3] = (short)f2bf(a0[3]);
        af[4] = (short)f2bf(a1[0]); af[5] = (short)f2bf(a1[1]);
        af[6] = (short)f2bf(a1[2]); af[7] = (short)f2bf(a1[3]);
        short8 bfr = bp[kk * 4];
        acc = __builtin_amdgcn_mfma_f32_16x16x32_bf16(af, bfr, acc, 0, 0, 0);
    }
    if (khalf == 1) comb[mloc][lane] = acc;
    __syncthreads();
    if (khalf == 0) {
        f32x4 o = comb[mloc][lane];
        #pragma unroll
        for (int j = 0; j < 4; j++) {
            int m = mbase + quad * 4 + j;       // C row = x row
            scores[rw * LSEQ + m] = acc[j] + o[j];  // C col = head
        }
    }
}

// K3: per-head max and 1/sum(exp). 16 blocks.
__global__ __launch_bounds__(256) void k3_stats(
    const float* __restrict__ scores, float* __restrict__ m_ws, float* __restrict__ is_ws)
{
    __shared__ float red[4];
    __shared__ float red2[4];
    int h = blockIdx.x, tid = threadIdx.x;
    const float* sp = scores + h * LSEQ;
    float mx = -1e30f;
    for (int i = tid; i < LSEQ; i += 256) mx = fmaxf(mx, sp[i]);
    #pragma unroll
    for (int off = 32; off > 0; off >>= 1) mx = fmaxf(mx, __shfl_xor(mx, off, 64));
    if ((tid & 63) == 0) red[tid >> 6] = mx;
    __syncthreads();
    mx = fmaxf(fmaxf(red[0], red[1]), fmaxf(red[2], red[3]));
    float sum = 0.f;
    for (int i = tid; i < LSEQ; i += 256) sum += __expf(sp[i] - mx);
    sum = wave_reduce_sum(sum);
    if ((tid & 63) == 0) red2[tid >> 6] = sum;
    __syncthreads();
    sum = red2[0] + red2[1] + red2[2] + red2[3];
    if (tid == 0) { m_ws[h] = mx; is_ws[h] = 1.f / sum; }
}

// K4: partial[chunk][h][e] = sum_{l in chunk} p[h,l] * x[l,e]
// grid nchunk*4: qc = b&3 (256 cols), chunk = b>>2. Thread: 1 col x 16 heads.
__global__ __launch_bounds__(256) void k4_partial(
    const float* __restrict__ x,
    const float* __restrict__ scores,
    const float* __restrict__ m_ws, const float* __restrict__ is_ws,
    float* __restrict__ partial, int rows_per_chunk)
{
    __shared__ float p_lds[64 * 16];   // [l_in_tile][h]
    __shared__ float sm[16], si[16];
    int b = blockIdx.x;
    int chunk = b >> 2, qc = b & 3;
    int tid = threadIdx.x;
    int lbase = chunk * rows_per_chunk;
    int e0 = qc * 256 + tid;
    if (tid < 16) { sm[tid] = m_ws[tid]; si[tid] = is_ws[tid]; }
    float acc[16];
    #pragma unroll
    for (int h = 0; h < 16; h++) acc[h] = 0.f;

    for (int t0 = 0; t0 < rows_per_chunk; t0 += 64) {
        __syncthreads();
        #pragma unroll
        for (int j = 0; j < 4; j++) {
            int idx = tid * 4 + j;            // 0..1023
            int li = idx >> 4, hh = idx & 15;
            float sc = scores[hh * LSEQ + lbase + t0 + li];
            p_lds[idx] = __expf(sc - sm[hh]) * si[hh];
        }
        __syncthreads();
        #pragma unroll 8
        for (int li = 0; li < 64; li++) {
            float xv = x[(lbase + t0 + li) * E + e0];
            const f32x4* pp = (const f32x4*)&p_lds[li * 16];
            #pragma unroll
            for (int g = 0; g < 4; g++) {
                f32x4 pv = pp[g];
                acc[g * 4 + 0] += pv[0] * xv;
                acc[g * 4 + 1] += pv[1] * xv;
                acc[g * 4 + 2] += pv[2] * xv;
                acc[g * 4 + 3] += pv[3] * xv;
            }
        }
    }
    #pragma unroll
    for (int h = 0; h < 16; h++) partial[(chunk * 16 + h) * E + e0] = acc[h];
}

// K4b: y[h*1024+e] = sum_chunks partial. 256 blocks, 64 outputs each.
__global__ __launch_bounds__(256) void k4b_reduce(
    const float* __restrict__ partial, float* __restrict__ y, int nchunk)
{
    __shared__ float red[4][64];
    int lane = threadIdx.x & 63, cq = threadIdx.x >> 6;
    int o = blockIdx.x * 64 + lane;        // 0..16383
    float s = 0.f;
    for (int c = cq; c < nchunk; c += 4) s += partial[c * (H * E) + o];
    red[cq][lane] = s;
    __syncthreads();
    if (cq == 0) y[o] = red[0][lane] + red[1][lane] + red[2][lane] + red[3][lane];
}

// K5a: oh[i] = Wv[i,:] . y_h + bv[i]   (i = h*64+d). One wave per output.
__global__ __launch_bounds__(256) void k5a_oh(
    const float* __restrict__ W, const float* __restrict__ bias,
    const float* __restrict__ y, float* __restrict__ oh)
{
    int wave = threadIdx.x >> 6, lane = threadIdx.x & 63;
    int i = blockIdx.x * 4 + wave;
    int h = i >> 6;
    const f32x4* wp = (const f32x4*)(W + (2 * E + i) * E) + lane * 4;
    const f32x4* yp = (const f32x4*)(y + h * E) + lane * 4;
    float s = 0.f;
    #pragma unroll
    for (int j = 0; j < 4; j++) {
        f32x4 w4 = wp[j], y4 = yp[j];
        s += w4[0] * y4[0] + w4[1] * y4[1] + w4[2] * y4[2] + w4[3] * y4[3];
    }
    s = wave_reduce_sum(s);
    if (lane == 0) oh[i] = s + bias[2 * E + i];
}

// K5b: out[j] = Wout[j,:] . oh + bout[j], fp32 out. One wave per output.
__global__ __launch_bounds__(256) void k5b_out(
    const float* __restrict__ Wout, const float* __restrict__ bout,
    const float* __restrict__ oh, float* __restrict__ out)
{
    int wave = threadIdx.x >> 6, lane = threadIdx.x & 63;
    int j = blockIdx.x * 4 + wave;
    const f32x4* wp = (const f32x4*)(Wout + j * E) + lane * 4;
    const f32x4* op = (const f32x4*)(oh) + lane * 4;
    float s = 0.f;
    #pragma unroll
    for (int jj = 0; jj < 4; jj++) {
        f32x4 w4 = wp[jj], o4 = op[jj];
        s += w4[0] * o4[0] + w4[1] * o4[1] + w4[2] * o4[2] + w4[3] * o4[3];
    }
    s = wave_reduce_sum(s);
    if (lane == 0) out[j] = s + bout[j];
}

extern "C" void kernel_launch(void* const* d_in, const int* in_sizes, int n_in,
                              void* d_out, int out_size, void* d_ws, size_t ws_size,
                              hipStream_t stream) {
    const float* x  = (const float*)d_in[0];
    const float* W  = (const float*)d_in[1];
    const float* b  = (const float*)d_in[2];
    const float* Wo = (const float*)d_in[3];
    const float* bo = (const float*)d_in[4];
    float* out = (float*)d_out;
    char* ws = (char*)d_ws;

    float* q_ws  = (float*)(ws);                 // 4096 B
    float* c_ws  = (float*)(ws + 4096);          // 64 B
    float* m_ws  = (float*)(ws + 4160);          // 64 B
    float* is_ws = (float*)(ws + 4224);          // 64 B
    float* oh_ws = (float*)(ws + 4352);          // 4096 B
    unsigned short* r_bf = (unsigned short*)(ws + 8448);    // 32768 B
    float* scores = (float*)(ws + 8448 + 32768);            // 524288 B @ 41216
    float* y_ws   = (float*)(ws + 41216 + 524288);          // 65536 B @ 565504
    float* partial = (float*)(ws + 565504 + 65536);         // @ 631040

    int nchunk = 64;  // partial needs nchunk*65536 B
    while (nchunk > 4 && (size_t)631040 + (size_t)nchunk * 65536 > ws_size) nchunk >>= 1;
    int rows_per_chunk = LSEQ / nchunk;

    hipLaunchKernelGGL(k0_q,      dim3(256), dim3(256), 0, stream, x, W, b, q_ws);
    hipLaunchKernelGGL(k1_rc,     dim3(256), dim3(256), 0, stream, W, b, q_ws, r_bf, c_ws);
    hipLaunchKernelGGL(k2_scores, dim3(256), dim3(256), 0, stream, x, r_bf, c_ws, scores);
    hipLaunchKernelGGL(k3_stats,  dim3(16),  dim3(256), 0, stream, scores, m_ws, is_ws);
    hipLaunchKernelGGL(k4_partial,dim3(nchunk * 4), dim3(256), 0, stream,
                       x, scores, m_ws, is_ws, partial, rows_per_chunk);
    hipLaunchKernelGGL(k4b_reduce,dim3(256), dim3(256), 0, stream, partial, y_ws, nchunk);
    hipLaunchKernelGGL(k5a_oh,    dim3(256), dim3(256), 0, stream, W, b, y_ws, oh_ws);
    hipLaunchKernelGGL(k5b_out,   dim3(256), dim3(256), 0, stream, Wo, bo, oh_ws, out);
}